// Round 1
// baseline (333.183 us; speedup 1.0000x reference)
//
#include <hip/hip_runtime.h>
#include <hip/hip_bf16.h>

#define B_DIM 4
#define S_DIM 2048
#define D_DIM 1024
#define H_DIM 16
#define HD_DIM 64

using bf16 = __hip_bfloat16;
using bf16x8 = __attribute__((ext_vector_type(8))) short;
using f32x4 = __attribute__((ext_vector_type(4))) float;

__device__ inline short f2bfs(float f) {
    bf16 h = __float2bfloat16(f);
    short s;
    __builtin_memcpy(&s, &h, 2);
    return s;
}

// ---------------------------------------------------------------------------
// Kernel 1: fp32 -> bf16 conversion (vectorized float4 -> 4x bf16)
// ---------------------------------------------------------------------------
__global__ __launch_bounds__(256) void conv_bf16_kernel(const float* __restrict__ in,
                                                        bf16* __restrict__ out, int n4) {
    int i = blockIdx.x * 256 + threadIdx.x;
    if (i >= n4) return;
    float4 v = reinterpret_cast<const float4*>(in)[i];
    ushort4 o;
    o.x = (unsigned short)f2bfs(v.x);
    o.y = (unsigned short)f2bfs(v.y);
    o.z = (unsigned short)f2bfs(v.z);
    o.w = (unsigned short)f2bfs(v.w);
    reinterpret_cast<ushort4*>(out)[i] = o;
}

// ---------------------------------------------------------------------------
// Kernel 2: fp32 [R][C] -> bf16 [C][R] transpose (LDS 32x32 tile)
// ---------------------------------------------------------------------------
__global__ __launch_bounds__(256) void transpose_bf16_kernel(const float* __restrict__ in,
                                                             bf16* __restrict__ out,
                                                             int R, int C) {
    __shared__ float tile[32][33];
    int c0 = blockIdx.x * 32, r0 = blockIdx.y * 32;
    int tx = threadIdx.x, ty = threadIdx.y;  // 32 x 8
#pragma unroll
    for (int i = 0; i < 32; i += 8)
        tile[ty + i][tx] = in[(size_t)(r0 + ty + i) * C + c0 + tx];
    __syncthreads();
#pragma unroll
    for (int i = 0; i < 32; i += 8)
        out[(size_t)(c0 + ty + i) * R + r0 + tx] = __float2bfloat16(tile[tx][ty + i]);
}

// ---------------------------------------------------------------------------
// Kernel 3: QKV GEMM. A = x_bf16 [8192][1024], BT = w_qkv^T bf16 [3072][1024].
// Epilogue: + bias, scatter to Q/K/V [B,H,S,HD] bf16.
// 128x128 tile, 256 threads (4 waves, each 64x64 via 4x4 16x16x32 mfma).
// ---------------------------------------------------------------------------
__global__ __launch_bounds__(256) void gemm_qkv_kernel(const bf16* __restrict__ A,
                                                       const bf16* __restrict__ BT,
                                                       const float* __restrict__ bias,
                                                       bf16* __restrict__ Qo,
                                                       bf16* __restrict__ Ko,
                                                       bf16* __restrict__ Vo) {
    const int K = D_DIM;
    __shared__ bf16 As[128][32];
    __shared__ bf16 Bs[128][32];
    int m0 = blockIdx.y * 128;
    int n0 = blockIdx.x * 128;
    int tid = threadIdx.x;
    int lane = tid & 63;
    int w = tid >> 6;
    int wr = w >> 1, wc = w & 1;
    int lr = lane & 15, lk = lane >> 4;
    f32x4 acc[4][4] = {};
    int sr = tid >> 2;
    int sc = (tid & 3) * 8;
    for (int k0 = 0; k0 < K; k0 += 32) {
        __syncthreads();
        *reinterpret_cast<bf16x8*>(&As[sr][sc]) =
            *reinterpret_cast<const bf16x8*>(&A[(size_t)(m0 + sr) * K + k0 + sc]);
        *reinterpret_cast<bf16x8*>(&As[sr + 64][sc]) =
            *reinterpret_cast<const bf16x8*>(&A[(size_t)(m0 + sr + 64) * K + k0 + sc]);
        *reinterpret_cast<bf16x8*>(&Bs[sr][sc]) =
            *reinterpret_cast<const bf16x8*>(&BT[(size_t)(n0 + sr) * K + k0 + sc]);
        *reinterpret_cast<bf16x8*>(&Bs[sr + 64][sc]) =
            *reinterpret_cast<const bf16x8*>(&BT[(size_t)(n0 + sr + 64) * K + k0 + sc]);
        __syncthreads();
        bf16x8 af[4], bfr[4];
#pragma unroll
        for (int m = 0; m < 4; ++m)
            af[m] = *reinterpret_cast<const bf16x8*>(&As[wr * 64 + m * 16 + lr][lk * 8]);
#pragma unroll
        for (int n = 0; n < 4; ++n)
            bfr[n] = *reinterpret_cast<const bf16x8*>(&Bs[wc * 64 + n * 16 + lr][lk * 8]);
#pragma unroll
        for (int m = 0; m < 4; ++m)
#pragma unroll
            for (int n = 0; n < 4; ++n)
                acc[m][n] = __builtin_amdgcn_mfma_f32_16x16x32_bf16(af[m], bfr[n], acc[m][n], 0, 0, 0);
    }
    // epilogue: bias + scatter into [B,H,S,HD]
#pragma unroll
    for (int m = 0; m < 4; ++m) {
        int row = m0 + wr * 64 + m * 16 + lk * 4;
#pragma unroll
        for (int n = 0; n < 4; ++n) {
            int col = n0 + wc * 64 + n * 16 + lr;
            int t = col >> 10;
            int rem = col & 1023;
            int h = rem >> 6, hd = rem & 63;
            bf16* dst = (t == 0) ? Qo : (t == 1 ? Ko : Vo);
            float bv = bias[col];
#pragma unroll
            for (int i = 0; i < 4; ++i) {
                int r = row + i;
                int b = r >> 11, s = r & 2047;
                dst[(((size_t)b * H_DIM + h) * S_DIM + s) * HD_DIM + hd] =
                    __float2bfloat16(acc[m][n][i] + bv);
            }
        }
    }
}

// ---------------------------------------------------------------------------
// Kernel 4: causal flash attention.
// grid (B*H, S/64), 256 threads = 4 waves; each wave owns 16 q-rows.
// KVBLK = 32. Q,K,V in [B,H,S,HD] bf16. Output attn [B,S,D] bf16.
// ---------------------------------------------------------------------------
__global__ __launch_bounds__(256) void attn_kernel(const bf16* __restrict__ Q,
                                                   const bf16* __restrict__ K,
                                                   const bf16* __restrict__ V,
                                                   bf16* __restrict__ Aout) {
    __shared__ short P_lds[4][16][32];
    int bh = blockIdx.x;
    int b = bh >> 4, h = bh & 15;
    int w = threadIdx.x >> 6;
    int lane = threadIdx.x & 63;
    int lr = lane & 15, lk = lane >> 4;
    int q0 = blockIdx.y * 64 + w * 16;

    const short* Qs = reinterpret_cast<const short*>(Q + ((size_t)bh * S_DIM + q0) * HD_DIM);
    const short* Ks = reinterpret_cast<const short*>(K + (size_t)bh * S_DIM * HD_DIM);
    const short* Vs = reinterpret_cast<const short*>(V + (size_t)bh * S_DIM * HD_DIM);

    bf16x8 qf[2];
    qf[0] = *reinterpret_cast<const bf16x8*>(&Qs[lr * HD_DIM + lk * 8]);
    qf[1] = *reinterpret_cast<const bf16x8*>(&Qs[lr * HD_DIM + 32 + lk * 8]);

    f32x4 o[4] = {};
    float m_run[4], l_run[4];
#pragma unroll
    for (int i = 0; i < 4; ++i) { m_run[i] = -1e30f; l_run[i] = 0.0f; }

    const float scale = 0.125f;  // 1/sqrt(64)
    int ntiles = (q0 + 47) >> 5;

    for (int t = 0; t < ntiles; ++t) {
        int kv = t * 32;
        // --- QK^T: two 16x16 halves, K=64 in 2 chunks ---
        f32x4 s0 = {}, s1 = {};
        {
            const short* Kr0 = &Ks[(kv + lr) * HD_DIM];
            const short* Kr1 = &Ks[(kv + 16 + lr) * HD_DIM];
            bf16x8 k00 = *reinterpret_cast<const bf16x8*>(&Kr0[lk * 8]);
            bf16x8 k01 = *reinterpret_cast<const bf16x8*>(&Kr0[32 + lk * 8]);
            bf16x8 k10 = *reinterpret_cast<const bf16x8*>(&Kr1[lk * 8]);
            bf16x8 k11 = *reinterpret_cast<const bf16x8*>(&Kr1[32 + lk * 8]);
            s0 = __builtin_amdgcn_mfma_f32_16x16x32_bf16(qf[0], k00, s0, 0, 0, 0);
            s0 = __builtin_amdgcn_mfma_f32_16x16x32_bf16(qf[1], k01, s0, 0, 0, 0);
            s1 = __builtin_amdgcn_mfma_f32_16x16x32_bf16(qf[0], k10, s1, 0, 0, 0);
            s1 = __builtin_amdgcn_mfma_f32_16x16x32_bf16(qf[1], k11, s1, 0, 0, 0);
        }
        bool need_mask = (kv + 31 > q0);
        // --- online softmax (rows owned: lk*4+i; cols: lr and 16+lr) ---
#pragma unroll
        for (int i = 0; i < 4; ++i) {
            float sv0 = s0[i] * scale;
            float sv1 = s1[i] * scale;
            if (need_mask) {
                int qrow = q0 + lk * 4 + i;
                if (kv + lr > qrow) sv0 = -1e30f;
                if (kv + 16 + lr > qrow) sv1 = -1e30f;
            }
            float mx = fmaxf(sv0, sv1);
            mx = fmaxf(mx, __shfl_xor(mx, 1));
            mx = fmaxf(mx, __shfl_xor(mx, 2));
            mx = fmaxf(mx, __shfl_xor(mx, 4));
            mx = fmaxf(mx, __shfl_xor(mx, 8));
            float mn = fmaxf(m_run[i], mx);
            float corr = __expf(m_run[i] - mn);
            float p0 = __expf(sv0 - mn);
            float p1 = __expf(sv1 - mn);
            float ps = p0 + p1;
            ps += __shfl_xor(ps, 1);
            ps += __shfl_xor(ps, 2);
            ps += __shfl_xor(ps, 4);
            ps += __shfl_xor(ps, 8);
            l_run[i] = l_run[i] * corr + ps;
            m_run[i] = mn;
#pragma unroll
            for (int n = 0; n < 4; ++n) o[n][i] *= corr;
            P_lds[w][lk * 4 + i][lr] = f2bfs(p0);
            P_lds[w][lk * 4 + i][16 + lr] = f2bfs(p1);
        }
        asm volatile("s_waitcnt lgkmcnt(0)" ::: "memory");
        bf16x8 pf = *reinterpret_cast<const bf16x8*>(&P_lds[w][lr][lk * 8]);
        // --- PV: O += P(16x32) * V(32x64), 4 n-chunks ---
#pragma unroll
        for (int n = 0; n < 4; ++n) {
            bf16x8 vf;
#pragma unroll
            for (int j = 0; j < 8; ++j)
                vf[j] = Vs[(size_t)(kv + lk * 8 + j) * HD_DIM + n * 16 + lr];
            o[n] = __builtin_amdgcn_mfma_f32_16x16x32_bf16(pf, vf, o[n], 0, 0, 0);
        }
    }
    // --- finalize: /l, write [B,S,H*HD] ---
    float inv[4];
#pragma unroll
    for (int i = 0; i < 4; ++i) inv[i] = 1.0f / l_run[i];
#pragma unroll
    for (int n = 0; n < 4; ++n)
#pragma unroll
        for (int i = 0; i < 4; ++i) {
            size_t srow = q0 + lk * 4 + i;
            Aout[((size_t)b * S_DIM + srow) * D_DIM + h * HD_DIM + n * 16 + lr] =
                __float2bfloat16(o[n][i] * inv[i]);
        }
}

// ---------------------------------------------------------------------------
// Kernel 5: output projection GEMM. A = attn bf16 [8192][1024],
// BT = w_out^T bf16 [1024][1024], bias fp32, out fp32 [8192][1024].
// ---------------------------------------------------------------------------
__global__ __launch_bounds__(256) void gemm_out_kernel(const bf16* __restrict__ A,
                                                       const bf16* __restrict__ BT,
                                                       const float* __restrict__ bias,
                                                       float* __restrict__ Out) {
    const int K = D_DIM;
    __shared__ bf16 As[128][32];
    __shared__ bf16 Bs[128][32];
    int m0 = blockIdx.y * 128;
    int n0 = blockIdx.x * 128;
    int tid = threadIdx.x;
    int lane = tid & 63;
    int w = tid >> 6;
    int wr = w >> 1, wc = w & 1;
    int lr = lane & 15, lk = lane >> 4;
    f32x4 acc[4][4] = {};
    int sr = tid >> 2;
    int sc = (tid & 3) * 8;
    for (int k0 = 0; k0 < K; k0 += 32) {
        __syncthreads();
        *reinterpret_cast<bf16x8*>(&As[sr][sc]) =
            *reinterpret_cast<const bf16x8*>(&A[(size_t)(m0 + sr) * K + k0 + sc]);
        *reinterpret_cast<bf16x8*>(&As[sr + 64][sc]) =
            *reinterpret_cast<const bf16x8*>(&A[(size_t)(m0 + sr + 64) * K + k0 + sc]);
        *reinterpret_cast<bf16x8*>(&Bs[sr][sc]) =
            *reinterpret_cast<const bf16x8*>(&BT[(size_t)(n0 + sr) * K + k0 + sc]);
        *reinterpret_cast<bf16x8*>(&Bs[sr + 64][sc]) =
            *reinterpret_cast<const bf16x8*>(&BT[(size_t)(n0 + sr + 64) * K + k0 + sc]);
        __syncthreads();
        bf16x8 af[4], bfr[4];
#pragma unroll
        for (int m = 0; m < 4; ++m)
            af[m] = *reinterpret_cast<const bf16x8*>(&As[wr * 64 + m * 16 + lr][lk * 8]);
#pragma unroll
        for (int n = 0; n < 4; ++n)
            bfr[n] = *reinterpret_cast<const bf16x8*>(&Bs[wc * 64 + n * 16 + lr][lk * 8]);
#pragma unroll
        for (int m = 0; m < 4; ++m)
#pragma unroll
            for (int n = 0; n < 4; ++n)
                acc[m][n] = __builtin_amdgcn_mfma_f32_16x16x32_bf16(af[m], bfr[n], acc[m][n], 0, 0, 0);
    }
#pragma unroll
    for (int m = 0; m < 4; ++m) {
        int row = m0 + wr * 64 + m * 16 + lk * 4;
#pragma unroll
        for (int n = 0; n < 4; ++n) {
            int col = n0 + wc * 64 + n * 16 + lr;
            float bv = bias[col];
#pragma unroll
            for (int i = 0; i < 4; ++i)
                Out[(size_t)(row + i) * D_DIM + col] = acc[m][n][i] + bv;
        }
    }
}

// ---------------------------------------------------------------------------
extern "C" void kernel_launch(void* const* d_in, const int* in_sizes, int n_in,
                              void* d_out, int out_size, void* d_ws, size_t ws_size,
                              hipStream_t stream) {
    const float* x = (const float*)d_in[0];      // [4,2048,1024]
    const float* w_qkv = (const float*)d_in[1];  // [1024,3072]
    const float* b_qkv = (const float*)d_in[2];  // [3072]
    const float* w_out = (const float*)d_in[3];  // [1024,1024]
    const float* b_out = (const float*)d_in[4];  // [1024]
    float* out = (float*)d_out;                  // [4,2048,1024] fp32

    char* ws = (char*)d_ws;
    const size_t SZ_X = (size_t)B_DIM * S_DIM * D_DIM * 2;     // 16.78 MB
    const size_t SZ_WQKV = (size_t)D_DIM * 3 * D_DIM * 2;      // 6.29 MB
    const size_t SZ_WOUT = (size_t)D_DIM * D_DIM * 2;          // 2.10 MB
    bf16* xb = (bf16*)(ws);                      // also reused as attn output
    bf16* wqkvT = (bf16*)(ws + SZ_X);
    bf16* woutT = (bf16*)(ws + SZ_X + SZ_WQKV);
    bf16* Qb = (bf16*)(ws + SZ_X + SZ_WQKV + SZ_WOUT);
    bf16* Kb = (bf16*)(ws + SZ_X + SZ_WQKV + SZ_WOUT + SZ_X);
    bf16* Vb = (bf16*)(ws + SZ_X + SZ_WQKV + SZ_WOUT + 2 * SZ_X);

    // 1) x -> bf16
    {
        int n4 = (B_DIM * S_DIM * D_DIM) / 4;
        conv_bf16_kernel<<<n4 / 256, 256, 0, stream>>>(x, xb, n4);
    }
    // 2) w_qkv^T -> bf16 [3072][1024]
    transpose_bf16_kernel<<<dim3(3 * D_DIM / 32, D_DIM / 32), dim3(32, 8), 0, stream>>>(
        w_qkv, wqkvT, D_DIM, 3 * D_DIM);
    // 3) w_out^T -> bf16 [1024][1024]
    transpose_bf16_kernel<<<dim3(D_DIM / 32, D_DIM / 32), dim3(32, 8), 0, stream>>>(
        w_out, woutT, D_DIM, D_DIM);
    // 4) QKV projection GEMM (+bias, scatter to [B,H,S,HD])
    gemm_qkv_kernel<<<dim3(3 * D_DIM / 128, B_DIM * S_DIM / 128), 256, 0, stream>>>(
        xb, wqkvT, b_qkv, Qb, Kb, Vb);
    // 5) causal flash attention -> attn bf16 [B,S,D] (reuses xb buffer)
    attn_kernel<<<dim3(B_DIM * H_DIM, S_DIM / 64), 256, 0, stream>>>(Qb, Kb, Vb, xb);
    // 6) output projection GEMM (+bias) -> fp32 d_out
    gemm_out_kernel<<<dim3(D_DIM / 128, B_DIM * S_DIM / 128), 256, 0, stream>>>(
        xb, woutT, b_out, out);
}